// Round 15
// baseline (130.881 us; speedup 1.0000x reference)
//
#include <hip/hip_runtime.h>

typedef short bf16x8 __attribute__((ext_vector_type(8)));
typedef float f32x4 __attribute__((ext_vector_type(4)));

__device__ __forceinline__ unsigned short f2bf(float f) {
    unsigned int u = __builtin_bit_cast(unsigned int, f);
    u = (u + 0x7FFFu + ((u >> 16) & 1u)) >> 16;
    return (unsigned short)u;
}
__device__ __forceinline__ float bf2f(unsigned short h) {
    unsigned int u = ((unsigned int)h) << 16;
    return __builtin_bit_cast(float, u);
}
__device__ __forceinline__ float dot4(f32x4 a, f32x4 b) {
    return a[0] * b[0] + a[1] * b[1] + a[2] * b[2] + a[3] * b[3];
}

// ---------------------------------------------------------------------------
// All three weight converts in one launch.
__global__ __launch_bounds__(256) void k_f2bf3(const float* __restrict__ W_in,
                                               const float* __restrict__ W_xp,
                                               const float* __restrict__ W_out,
                                               unsigned int* __restrict__ Winb,
                                               unsigned int* __restrict__ Wxpb,
                                               unsigned int* __restrict__ Woutb) {
    int tid = blockIdx.x * 256 + threadIdx.x;
    const float* src; unsigned int* dst; int idx;
    if (tid < 65536)       { src = W_in;  dst = Winb;  idx = tid; }
    else if (tid < 71680)  { src = W_xp;  dst = Wxpb;  idx = tid - 65536; }
    else if (tid < 104448) { src = W_out; dst = Woutb; idx = tid - 71680; }
    else return;
    float4 v = ((const float4*)src)[idx];
    uint2 o;
    o.x = (unsigned int)f2bf(v.x) | ((unsigned int)f2bf(v.y) << 16);
    o.y = (unsigned int)f2bf(v.z) | ((unsigned int)f2bf(v.w) << 16);
    ((uint2*)dst)[idx] = o;
}

// ---------------------------------------------------------------------------
// GEMM1 + fused x-permute/convert + fused conv(4) + SiLU.
// (R14 post-mortem: A-traffic is 8x fp32 x re-read ~536MB L2/L3 ~= 15us of
// this kernel's time; known, accepted -- restructuring trades into the
// measured register-pressure cliff.)
__global__ __launch_bounds__(256, 2) void k_gemm1(const float* __restrict__ x,
                                                  const unsigned short* __restrict__ Bw,
                                                  const float* __restrict__ Wc,
                                                  const float* __restrict__ bcv,
                                                  unsigned short* __restrict__ ub,
                                                  unsigned short* __restrict__ z) {
    __shared__ char smem[65536];   // As/Bs dbuf (2x32KB); xpS[128][132] aliases
    unsigned short (*As)[128][64] = (unsigned short (*)[128][64])smem;
    unsigned short (*Bs)[128][64] = (unsigned short (*)[128][64])(smem + 32768);
    unsigned short (*xpS)[132]    = (unsigned short (*)[132])smem;
    const int tid = threadIdx.x;
    const int l = tid & 63, w = tid >> 6;
    const int lr = l & 15, lg = l >> 4;
    const int wr = w >> 1, wc = w & 1;
    const int bb = blockIdx.x >> 6, nn = blockIdx.x & 63;   // bn = blockIdx.x
    const int row0 = blockIdx.x * 128;
    const int n0b  = blockIdx.y * 128;

    bf16x8 sa[4], sb[4];
    auto LOAD = [&](int k0) {
        #pragma unroll
        for (int r2 = 0; r2 < 4; ++r2) {
            int cc = tid + r2 * 256;
            int row = cc >> 3, ke = (cc & 7) * 8;
            const float* srcA = x + ((size_t)((bb * 128 + row) * 64 + nn) << 8) + k0 + ke;
            float4 v0 = *(const float4*)srcA;
            float4 v1 = *(const float4*)(srcA + 4);
            bf16x8 t8;
            t8[0] = (short)f2bf(v0.x); t8[1] = (short)f2bf(v0.y);
            t8[2] = (short)f2bf(v0.z); t8[3] = (short)f2bf(v0.w);
            t8[4] = (short)f2bf(v1.x); t8[5] = (short)f2bf(v1.y);
            t8[6] = (short)f2bf(v1.z); t8[7] = (short)f2bf(v1.w);
            sa[r2] = t8;
            sb[r2] = *(const bf16x8*)(Bw + (size_t)(n0b + row) * 256 + k0 + ke);
        }
    };
    auto WRITE = [&](int buf) {
        #pragma unroll
        for (int r2 = 0; r2 < 4; ++r2) {
            int cc = tid + r2 * 256;
            int row = cc >> 3, ke = (cc & 7) * 8;
            int ks = ke ^ ((row & 7) * 8);
            *(bf16x8*)&As[buf][row][ks] = sa[r2];
            *(bf16x8*)&Bs[buf][row][ks] = sb[r2];
        }
    };

    f32x4 acc[4][4] = {};
    LOAD(0); WRITE(0);
    __syncthreads();
    int cur = 0;
    for (int kt = 0; kt < 4; ++kt) {
        if (kt < 3) LOAD((kt + 1) * 64);
        #pragma unroll
        for (int ks = 0; ks < 2; ++ks) {
            const int ka = ks * 32;
            bf16x8 a[4], b[4];
            #pragma unroll
            for (int mi = 0; mi < 4; ++mi) {
                int row = wr * 64 + mi * 16 + lr;
                int e = (ka + lg * 8) ^ ((row & 7) * 8);
                a[mi] = *(const bf16x8*)&As[cur][row][e];
            }
            #pragma unroll
            for (int ni = 0; ni < 4; ++ni) {
                int row = wc * 64 + ni * 16 + lr;
                int e = (ka + lg * 8) ^ ((row & 7) * 8);
                b[ni] = *(const bf16x8*)&Bs[cur][row][e];
            }
            #pragma unroll
            for (int mi = 0; mi < 4; ++mi)
                #pragma unroll
                for (int ni = 0; ni < 4; ++ni)
                    acc[mi][ni] = __builtin_amdgcn_mfma_f32_16x16x32_bf16(a[mi], b[ni], acc[mi][ni], 0, 0, 0);
        }
        if (kt < 3) WRITE(cur ^ 1);
        __syncthreads();   // last iter: all As/Bs reads done -> safe to alias
        cur ^= 1;
    }
    if (blockIdx.y >= 4) {
        unsigned short* dst = z;
        const int colbase = (blockIdx.y - 4) * 128 + wc * 64;
        #pragma unroll
        for (int mi = 0; mi < 4; ++mi)
            #pragma unroll
            for (int r = 0; r < 4; ++r) {
                const int row = row0 + wr * 64 + mi * 16 + lg * 4 + r;
                #pragma unroll
                for (int ni = 0; ni < 4; ++ni)
                    dst[(size_t)row * 512 + colbase + ni * 16 + lr] = f2bf(acc[mi][ni][r]);
            }
    } else {
        // xp path: acc -> LDS tile -> conv(4)+SiLU -> ub
        #pragma unroll
        for (int mi = 0; mi < 4; ++mi)
            #pragma unroll
            for (int r = 0; r < 4; ++r) {
                const int trow = wr * 64 + mi * 16 + lg * 4 + r;
                #pragma unroll
                for (int ni = 0; ni < 4; ++ni)
                    xpS[trow][wc * 64 + ni * 16 + lr] = f2bf(acc[mi][ni][r]);
            }
        __syncthreads();
        const int d2 = tid & 63;
        const int dloc = d2 << 1;
        const int dglob = blockIdx.y * 128 + dloc;
        f32x4 wa = *(const f32x4*)(Wc + dglob * 4);
        f32x4 wb = *(const f32x4*)(Wc + dglob * 4 + 4);
        const float b0 = bcv[dglob], b1 = bcv[dglob + 1];
        unsigned int* dst = (unsigned int*)(ub + (size_t)blockIdx.x * 65536 + dglob);
        const int tbase = tid >> 6;
        #pragma unroll 1
        for (int i = 0; i < 32; ++i) {
            const int t = tbase + i * 4;
            float a0 = b0, a1 = b1;
            #pragma unroll
            for (int k = 0; k < 4; ++k) {
                int tt = t - 3 + k;
                if (tt >= 0) {
                    unsigned int pv = *(const unsigned int*)&xpS[tt][dloc];
                    a0 += bf2f((unsigned short)(pv & 0xFFFFu)) * wa[k];
                    a1 += bf2f((unsigned short)(pv >> 16)) * wb[k];
                }
            }
            float u0 = a0 / (1.f + __expf(-a0));
            float u1 = a1 / (1.f + __expf(-a1));
            dst[(size_t)t * 256] = (unsigned int)f2bf(u0) | ((unsigned int)f2bf(u1) << 16);
        }
    }
}

// ---------------------------------------------------------------------------
// x_dbl[16384 x 48] = u_bf[16384 x 512] @ W_xproj_bf[48 x 512]^T  (fp32 out)
__global__ __launch_bounds__(256, 2) void k_xproj(const unsigned short* __restrict__ U,
                                                  const unsigned short* __restrict__ Wb,
                                                  float* __restrict__ xdbl) {
    const int w = threadIdx.x >> 6, l = threadIdx.x & 63;
    const int lr = l & 15, lg = l >> 4;
    const int row0 = blockIdx.x * 64 + w * 16;
    f32x4 acc[3] = {};
    for (int k0 = 0; k0 < 512; k0 += 32) {
        const int ka = k0 + lg * 8;
        bf16x8 a = *(const bf16x8*)(U + (size_t)(row0 + lr) * 512 + ka);
        bf16x8 b[3];
        #pragma unroll
        for (int ni = 0; ni < 3; ++ni)
            b[ni] = *(const bf16x8*)(Wb + (size_t)(ni * 16 + lr) * 512 + ka);
        #pragma unroll
        for (int ni = 0; ni < 3; ++ni)
            acc[ni] = __builtin_amdgcn_mfma_f32_16x16x32_bf16(a, b[ni], acc[ni], 0, 0, 0);
    }
    #pragma unroll
    for (int r = 0; r < 4; ++r) {
        const int row = row0 + lg * 4 + r;
        #pragma unroll
        for (int ni = 0; ni < 3; ++ni)
            xdbl[(size_t)row * 48 + ni * 16 + lr] = acc[ni][r];
    }
}

// ---------------------------------------------------------------------------
// Chunked parallel selective scan v12 = v11 with unroll 2 -> 4 on hot loops.
// Evidence: unroll1->2 gave 61->58.3us at VGPR 60 (no spill). Latency-bound
// (VALUBusy 67%, 4 waves/SIMD); unroll4 doubles in-flight iterations again.
// Tripwire: WRITE_SIZE >> 16.4MB -> spilled -> revert to 2.
__global__ __launch_bounds__(512, 2) void k_scan(const float* __restrict__ xdbl,
                                                 const unsigned short* __restrict__ ub,
                                                 const unsigned short* __restrict__ zb,
                                                 const float* __restrict__ W_dt,
                                                 const float* __restrict__ b_dt,
                                                 const float* __restrict__ A_log,
                                                 const float* __restrict__ Dp,
                                                 unsigned short* __restrict__ yb) {
    __shared__ float bc[128][48];         // [t][ dtr | B | C ]          24 KB
    __shared__ _Float16 dtS[128][128];    // [t][d]                      32 KB
    __shared__ _Float16 cP[3][16][128];   // [chunk][state][dg]          12 KB
    __shared__ _Float16 cH[3][16][128];   //                             12 KB
    const int bn = blockIdx.x >> 2;
    const int d0 = (blockIdx.x & 3) * 128;
    {
        const float* src = xdbl + (size_t)(bn * 128) * 48;
        #pragma unroll
        for (int k = 0; k < 3; ++k) {
            int li = threadIdx.x + k * 512;
            int row = li / 12, c4 = li - row * 12;
            *(f32x4*)(&bc[row][c4 * 4]) = *(const f32x4*)(src + row * 48 + c4 * 4);
        }
    }
    const int dg = threadIdx.x & 127;
    const int c  = threadIdx.x >> 7;
    const int d  = d0 + dg;
    bool fast = true;
    #pragma unroll
    for (int j = 0; j < 16; ++j) {
        float aj = __expf(A_log[d * 16 + j]);
        fast = fast && (fabsf(aj - (float)(j + 1)) < 1e-3f * (float)(j + 1));
    }
    f32x4 wd0 = *(const f32x4*)(W_dt + d * 16);
    f32x4 wd1 = *(const f32x4*)(W_dt + d * 16 + 4);
    f32x4 wd2 = *(const f32x4*)(W_dt + d * 16 + 8);
    f32x4 wd3 = *(const f32x4*)(W_dt + d * 16 + 12);
    const float dbias = b_dt[d];
    const unsigned short* up = ub + (size_t)bn * 65536 + d;
    const unsigned short* zp = zb + (size_t)bn * 65536 + d;
    unsigned short* yp = yb + (size_t)bn * 65536 + d;
    const int t0 = c * 32;
    __syncthreads();
    // --- pass 0: dt -> dtS ---
    #pragma unroll 4
    for (int i = 0; i < 32; ++i) {
        const int t = t0 + i;
        float dl = dbias
                 + dot4(wd0, *(const f32x4*)&bc[t][0])
                 + dot4(wd1, *(const f32x4*)&bc[t][4])
                 + dot4(wd2, *(const f32x4*)&bc[t][8])
                 + dot4(wd3, *(const f32x4*)&bc[t][12]);
        float dt = (dl > 20.f) ? dl : __logf(1.f + __expf(dl));
        dtS[t][dg] = (_Float16)dt;
    }
    float h[16], p[16];
    #pragma unroll
    for (int j = 0; j < 16; ++j) { h[j] = 0.f; p[j] = 1.f; }
    // --- pass 1: local scan (h0=0) + chunk product; chunks 0..2 only ---
    if (c < 3) {
        if (fast) {
            float S = 1.f;
            #pragma unroll 4
            for (int i = 0; i < 32; ++i) {
                const int t = t0 + i;
                float dtv = (float)dtS[t][dg];
                float du  = dtv * bf2f(up[t * 512]);
                float E = __expf(-dtv);
                S *= E;
                float E2 = E * E, E3 = E2 * E, E4 = E2 * E2;
                float E8 = E4 * E4, E12 = E8 * E4;
                f32x4 B0 = *(const f32x4*)&bc[t][16];
                f32x4 B1 = *(const f32x4*)&bc[t][20];
                f32x4 B2 = *(const f32x4*)&bc[t][24];
                f32x4 B3 = *(const f32x4*)&bc[t][28];
                h[0]  = h[0]  * E         + du * B0[0];
                h[1]  = h[1]  * E2        + du * B0[1];
                h[2]  = h[2]  * E3        + du * B0[2];
                h[3]  = h[3]  * E4        + du * B0[3];
                h[4]  = h[4]  * (E4 * E)  + du * B1[0];
                h[5]  = h[5]  * (E4 * E2) + du * B1[1];
                h[6]  = h[6]  * (E4 * E3) + du * B1[2];
                h[7]  = h[7]  * E8        + du * B1[3];
                h[8]  = h[8]  * (E8 * E)  + du * B2[0];
                h[9]  = h[9]  * (E8 * E2) + du * B2[1];
                h[10] = h[10] * (E8 * E3) + du * B2[2];
                h[11] = h[11] * E12       + du * B2[3];
                h[12] = h[12] * (E12 * E) + du * B3[0];
                h[13] = h[13] * (E12 * E2)+ du * B3[1];
                h[14] = h[14] * (E12 * E3)+ du * B3[2];
                h[15] = h[15] * (E12 * E4)+ du * B3[3];
            }
            float S2 = S * S, S3 = S2 * S, S4 = S2 * S2;
            float S8 = S4 * S4, S12 = S8 * S4;
            p[0] = S;        p[1] = S2;        p[2] = S3;        p[3] = S4;
            p[4] = S4 * S;   p[5] = S4 * S2;   p[6] = S4 * S3;   p[7] = S8;
            p[8] = S8 * S;   p[9] = S8 * S2;   p[10] = S8 * S3;  p[11] = S12;
            p[12] = S12 * S; p[13] = S12 * S2; p[14] = S12 * S3; p[15] = S12 * S4;
        } else {
            #pragma unroll 1
            for (int i = 0; i < 32; ++i) {
                const int t = t0 + i;
                float dtv = (float)dtS[t][dg];
                float du  = dtv * bf2f(up[t * 512]);
                #pragma unroll
                for (int j = 0; j < 16; ++j) {
                    float e = __expf(-dtv * __expf(A_log[d * 16 + j]));
                    h[j] = h[j] * e + du * bc[t][16 + j];
                    p[j] *= e;
                }
            }
        }
        #pragma unroll
        for (int s = 0; s < 16; ++s) {
            cP[c][s][dg] = (_Float16)p[s];
            cH[c][s][dg] = (_Float16)h[s];
        }
    }
    __syncthreads();
    // --- Hillis-Steele over chunks 0..2; group-of-4 combine ---
    #pragma unroll
    for (int s = 1; s < 4; s <<= 1) {
        const bool act = (c >= s) && (c < 3);
        __syncthreads();
        if (act) {
            #pragma unroll
            for (int g = 0; g < 4; ++g) {
                #pragma unroll
                for (int k = 0; k < 4; ++k) {
                    const int j = 4 * g + k;
                    float gv = (float)cH[c - s][j][dg];
                    float qv = (float)cP[c - s][j][dg];
                    h[j] += p[j] * gv;
                    p[j] *= qv;
                }
            }
        }
        __syncthreads();
        if (act) {
            #pragma unroll
            for (int j = 0; j < 16; ++j) {
                cP[c][j][dg] = (_Float16)p[j];
                cH[c][j][dg] = (_Float16)h[j];
            }
        }
    }
    __syncthreads();
    #pragma unroll
    for (int j = 0; j < 16; ++j) h[j] = 0.f;
    if (c > 0) {
        #pragma unroll
        for (int j = 0; j < 16; ++j) h[j] = (float)cH[c - 1][j][dg];
    }
    // --- pass 2: rescan from true entry state, emit y ---
    const float dpar = Dp[d];
    if (fast) {
        #pragma unroll 4
        for (int i = 0; i < 32; ++i) {
            const int t = t0 + i;
            float dtv = (float)dtS[t][dg];
            float uv  = bf2f(up[t * 512]);
            float zv  = bf2f(zp[t * 512]);
            float du = dtv * uv;
            float E = __expf(-dtv);
            float E2 = E * E, E3 = E2 * E, E4 = E2 * E2;
            float E8 = E4 * E4, E12 = E8 * E4;
            f32x4 B0 = *(const f32x4*)&bc[t][16];
            f32x4 B1 = *(const f32x4*)&bc[t][20];
            f32x4 B2 = *(const f32x4*)&bc[t][24];
            f32x4 B3 = *(const f32x4*)&bc[t][28];
            f32x4 C0 = *(const f32x4*)&bc[t][32];
            f32x4 C1 = *(const f32x4*)&bc[t][36];
            f32x4 C2 = *(const f32x4*)&bc[t][40];
            f32x4 C3 = *(const f32x4*)&bc[t][44];
            h[0]  = h[0]  * E         + du * B0[0];
            h[1]  = h[1]  * E2        + du * B0[1];
            h[2]  = h[2]  * E3        + du * B0[2];
            h[3]  = h[3]  * E4        + du * B0[3];
            h[4]  = h[4]  * (E4 * E)  + du * B1[0];
            h[5]  = h[5]  * (E4 * E2) + du * B1[1];
            h[6]  = h[6]  * (E4 * E3) + du * B1[2];
            h[7]  = h[7]  * E8        + du * B1[3];
            h[8]  = h[8]  * (E8 * E)  + du * B2[0];
            h[9]  = h[9]  * (E8 * E2) + du * B2[1];
            h[10] = h[10] * (E8 * E3) + du * B2[2];
            h[11] = h[11] * E12       + du * B2[3];
            h[12] = h[12] * (E12 * E) + du * B3[0];
            h[13] = h[13] * (E12 * E2)+ du * B3[1];
            h[14] = h[14] * (E12 * E3)+ du * B3[2];
            h[15] = h[15] * (E12 * E4)+ du * B3[3];
            float y0 = h[0] * C0[0] + h[1] * C0[1] + h[2] * C0[2] + h[3] * C0[3];
            float y1 = h[4] * C1[0] + h[5] * C1[1] + h[6] * C1[2] + h[7] * C1[3];
            float y2 = h[8] * C2[0] + h[9] * C2[1] + h[10] * C2[2] + h[11] * C2[3];
            float y3 = h[12] * C3[0] + h[13] * C3[1] + h[14] * C3[2] + h[15] * C3[3];
            float y = (y0 + y1) + (y2 + y3);
            float yf = (y + uv * dpar) * (zv / (1.f + __expf(-zv)));
            yp[t * 512] = f2bf(yf);
        }
    } else {
        #pragma unroll 1
        for (int i = 0; i < 32; ++i) {
            const int t = t0 + i;
            float dtv = (float)dtS[t][dg];
            float uv  = bf2f(up[t * 512]);
            float zv  = bf2f(zp[t * 512]);
            float du = dtv * uv;
            float y = 0.f;
            #pragma unroll
            for (int j = 0; j < 16; ++j) {
                float e = __expf(-dtv * __expf(A_log[d * 16 + j]));
                h[j] = h[j] * e + du * bc[t][16 + j];
                y += h[j] * bc[t][32 + j];
            }
            float yf = (y + uv * dpar) * (zv / (1.f + __expf(-zv)));
            yp[t * 512] = f2bf(yf);
        }
    }
}

// ---------------------------------------------------------------------------
// out = LayerNorm( y_bf[16384 x 512] @ W_out_bf[256 x 512]^T ) with permuted store.
__global__ __launch_bounds__(256, 2) void k_out_ln(const unsigned short* __restrict__ Y,
                                                   const unsigned short* __restrict__ Wb,
                                                   const float* __restrict__ gamma,
                                                   const float* __restrict__ beta,
                                                   float* __restrict__ out) {
    __shared__ float s_sum[32], s_sq[32];
    const int w = threadIdx.x >> 6, l = threadIdx.x & 63;
    const int lr = l & 15, lg = l >> 4;
    const int row0 = blockIdx.x * 32;
    const int n0 = w * 64;
    f32x4 acc[2][4] = {};
    for (int k0 = 0; k0 < 512; k0 += 32) {
        const int ka = k0 + lg * 8;
        bf16x8 a[2], b[4];
        #pragma unroll
        for (int mi = 0; mi < 2; ++mi)
            a[mi] = *(const bf16x8*)(Y + (size_t)(row0 + mi * 16 + lr) * 512 + ka);
        #pragma unroll
        for (int ni = 0; ni < 4; ++ni)
            b[ni] = *(const bf16x8*)(Wb + (size_t)(n0 + ni * 16 + lr) * 512 + ka);
        #pragma unroll
        for (int mi = 0; mi < 2; ++mi)
            #pragma unroll
            for (int ni = 0; ni < 4; ++ni)
                acc[mi][ni] = __builtin_amdgcn_mfma_f32_16x16x32_bf16(a[mi], b[ni], acc[mi][ni], 0, 0, 0);
    }
    if (threadIdx.x < 32) { s_sum[threadIdx.x] = 0.f; s_sq[threadIdx.x] = 0.f; }
    __syncthreads();
    #pragma unroll
    for (int mi = 0; mi < 2; ++mi)
        #pragma unroll
        for (int r = 0; r < 4; ++r) {
            float s = 0.f, q = 0.f;
            #pragma unroll
            for (int ni = 0; ni < 4; ++ni) { float v = acc[mi][ni][r]; s += v; q += v * v; }
            #pragma unroll
            for (int m = 1; m < 16; m <<= 1) { s += __shfl_xor(s, m, 64); q += __shfl_xor(q, m, 64); }
            if (lr == 0) {
                atomicAdd(&s_sum[mi * 16 + lg * 4 + r], s);
                atomicAdd(&s_sq[mi * 16 + lg * 4 + r], q);
            }
        }
    __syncthreads();
    float g[4], be[4];
    #pragma unroll
    for (int ni = 0; ni < 4; ++ni) {
        g[ni] = gamma[n0 + ni * 16 + lr];
        be[ni] = beta[n0 + ni * 16 + lr];
    }
    #pragma unroll
    for (int mi = 0; mi < 2; ++mi)
        #pragma unroll
        for (int r = 0; r < 4; ++r) {
            const int rl = mi * 16 + lg * 4 + r;
            const int row = row0 + rl;
            const float mu = s_sum[rl] * (1.f / 256.f);
            const float var = s_sq[rl] * (1.f / 256.f) - mu * mu;
            const float rs = rsqrtf(var + 1e-5f);
            const int t = row & 127, bn = row >> 7;
            const int nn = bn & 63, bb = bn >> 6;
            float* orow = out + ((((size_t)(bb * 128 + t)) * 64 + nn) << 8);
            #pragma unroll
            for (int ni = 0; ni < 4; ++ni)
                orow[n0 + ni * 16 + lr] = (acc[mi][ni][r] - mu) * rs * g[ni] + be[ni];
        }
}

// ---------------------------------------------------------------------------
extern "C" void kernel_launch(void* const* d_in, const int* in_sizes, int n_in,
                              void* d_out, int out_size, void* d_ws, size_t ws_size,
                              hipStream_t stream) {
    const float* x      = (const float*)d_in[0];
    const float* W_in   = (const float*)d_in[1];
    const float* W_conv = (const float*)d_in[2];
    const float* b_conv = (const float*)d_in[3];
    const float* W_xprj = (const float*)d_in[4];
    const float* W_dt   = (const float*)d_in[5];
    const float* b_dt   = (const float*)d_in[6];
    const float* A_log  = (const float*)d_in[7];
    const float* D_par  = (const float*)d_in[8];
    const float* W_out  = (const float*)d_in[9];
    const float* gamma  = (const float*)d_in[10];
    const float* beta   = (const float*)d_in[11];
    float* out = (float*)d_out;

    char* ws = (char*)d_ws;
    size_t off = 0;
    auto alloc = [&](size_t bytes) -> void* {
        void* p = ws + off;
        off += (bytes + 255) & ~(size_t)255;
        return p;
    };
    unsigned short* Winb  = (unsigned short*)alloc(1024ull * 256 * 2);
    unsigned short* Wxpb  = (unsigned short*)alloc(48ull * 512 * 2);
    unsigned short* Woutb = (unsigned short*)alloc(256ull * 512 * 2);
    unsigned short* zb    = (unsigned short*)alloc(16384ull * 512 * 2);
    unsigned short* ub    = (unsigned short*)alloc(16384ull * 512 * 2);
    float*          xdbl  = (float*)alloc(16384ull * 48 * 4);
    unsigned short* yb    = (unsigned short*)alloc(16384ull * 512 * 2);
    if (off > ws_size) return;

    k_f2bf3<<<408, 256, 0, stream>>>(W_in, W_xprj, W_out,
                                     (unsigned int*)Winb, (unsigned int*)Wxpb,
                                     (unsigned int*)Woutb);
    k_gemm1<<<dim3(128, 8), 256, 0, stream>>>(x, Winb, W_conv, b_conv, ub, zb);
    k_xproj<<<256, 256, 0, stream>>>(ub, Wxpb, xdbl);
    k_scan<<<512, 512, 0, stream>>>(xdbl, ub, zb, W_dt, b_dt, A_log, D_par, yb);
    k_out_ln<<<512, 256, 0, stream>>>(yb, Woutb, gamma, beta, out);
}

// Round 16
// 121.714 us; speedup vs baseline: 1.0753x; 1.0753x over previous
//
#include <hip/hip_runtime.h>

typedef short bf16x8 __attribute__((ext_vector_type(8)));
typedef float f32x4 __attribute__((ext_vector_type(4)));

__device__ __forceinline__ unsigned short f2bf(float f) {
    unsigned int u = __builtin_bit_cast(unsigned int, f);
    u = (u + 0x7FFFu + ((u >> 16) & 1u)) >> 16;
    return (unsigned short)u;
}
__device__ __forceinline__ float bf2f(unsigned short h) {
    unsigned int u = ((unsigned int)h) << 16;
    return __builtin_bit_cast(float, u);
}
__device__ __forceinline__ float dot4(f32x4 a, f32x4 b) {
    return a[0] * b[0] + a[1] * b[1] + a[2] * b[2] + a[3] * b[3];
}

// ---------------------------------------------------------------------------
// All three weight converts in one launch.
__global__ __launch_bounds__(256) void k_f2bf3(const float* __restrict__ W_in,
                                               const float* __restrict__ W_xp,
                                               const float* __restrict__ W_out,
                                               unsigned int* __restrict__ Winb,
                                               unsigned int* __restrict__ Wxpb,
                                               unsigned int* __restrict__ Woutb) {
    int tid = blockIdx.x * 256 + threadIdx.x;
    const float* src; unsigned int* dst; int idx;
    if (tid < 65536)       { src = W_in;  dst = Winb;  idx = tid; }
    else if (tid < 71680)  { src = W_xp;  dst = Wxpb;  idx = tid - 65536; }
    else if (tid < 104448) { src = W_out; dst = Woutb; idx = tid - 71680; }
    else return;
    float4 v = ((const float4*)src)[idx];
    uint2 o;
    o.x = (unsigned int)f2bf(v.x) | ((unsigned int)f2bf(v.y) << 16);
    o.y = (unsigned int)f2bf(v.z) | ((unsigned int)f2bf(v.w) << 16);
    ((uint2*)dst)[idx] = o;
}

// ---------------------------------------------------------------------------
// GEMM1 + fused x-permute/convert + fused conv(4) + SiLU.
// (A-traffic: 8x fp32 x re-read ~536MB L2/L3; known, accepted -- alternatives
// hit the measured register-pressure cliff.)
__global__ __launch_bounds__(256, 2) void k_gemm1(const float* __restrict__ x,
                                                  const unsigned short* __restrict__ Bw,
                                                  const float* __restrict__ Wc,
                                                  const float* __restrict__ bcv,
                                                  unsigned short* __restrict__ ub,
                                                  unsigned short* __restrict__ z) {
    __shared__ char smem[65536];   // As/Bs dbuf (2x32KB); xpS[128][132] aliases
    unsigned short (*As)[128][64] = (unsigned short (*)[128][64])smem;
    unsigned short (*Bs)[128][64] = (unsigned short (*)[128][64])(smem + 32768);
    unsigned short (*xpS)[132]    = (unsigned short (*)[132])smem;
    const int tid = threadIdx.x;
    const int l = tid & 63, w = tid >> 6;
    const int lr = l & 15, lg = l >> 4;
    const int wr = w >> 1, wc = w & 1;
    const int bb = blockIdx.x >> 6, nn = blockIdx.x & 63;   // bn = blockIdx.x
    const int row0 = blockIdx.x * 128;
    const int n0b  = blockIdx.y * 128;

    bf16x8 sa[4], sb[4];
    auto LOAD = [&](int k0) {
        #pragma unroll
        for (int r2 = 0; r2 < 4; ++r2) {
            int cc = tid + r2 * 256;
            int row = cc >> 3, ke = (cc & 7) * 8;
            const float* srcA = x + ((size_t)((bb * 128 + row) * 64 + nn) << 8) + k0 + ke;
            float4 v0 = *(const float4*)srcA;
            float4 v1 = *(const float4*)(srcA + 4);
            bf16x8 t8;
            t8[0] = (short)f2bf(v0.x); t8[1] = (short)f2bf(v0.y);
            t8[2] = (short)f2bf(v0.z); t8[3] = (short)f2bf(v0.w);
            t8[4] = (short)f2bf(v1.x); t8[5] = (short)f2bf(v1.y);
            t8[6] = (short)f2bf(v1.z); t8[7] = (short)f2bf(v1.w);
            sa[r2] = t8;
            sb[r2] = *(const bf16x8*)(Bw + (size_t)(n0b + row) * 256 + k0 + ke);
        }
    };
    auto WRITE = [&](int buf) {
        #pragma unroll
        for (int r2 = 0; r2 < 4; ++r2) {
            int cc = tid + r2 * 256;
            int row = cc >> 3, ke = (cc & 7) * 8;
            int ks = ke ^ ((row & 7) * 8);
            *(bf16x8*)&As[buf][row][ks] = sa[r2];
            *(bf16x8*)&Bs[buf][row][ks] = sb[r2];
        }
    };

    f32x4 acc[4][4] = {};
    LOAD(0); WRITE(0);
    __syncthreads();
    int cur = 0;
    for (int kt = 0; kt < 4; ++kt) {
        if (kt < 3) LOAD((kt + 1) * 64);
        #pragma unroll
        for (int ks = 0; ks < 2; ++ks) {
            const int ka = ks * 32;
            bf16x8 a[4], b[4];
            #pragma unroll
            for (int mi = 0; mi < 4; ++mi) {
                int row = wr * 64 + mi * 16 + lr;
                int e = (ka + lg * 8) ^ ((row & 7) * 8);
                a[mi] = *(const bf16x8*)&As[cur][row][e];
            }
            #pragma unroll
            for (int ni = 0; ni < 4; ++ni) {
                int row = wc * 64 + ni * 16 + lr;
                int e = (ka + lg * 8) ^ ((row & 7) * 8);
                b[ni] = *(const bf16x8*)&Bs[cur][row][e];
            }
            #pragma unroll
            for (int mi = 0; mi < 4; ++mi)
                #pragma unroll
                for (int ni = 0; ni < 4; ++ni)
                    acc[mi][ni] = __builtin_amdgcn_mfma_f32_16x16x32_bf16(a[mi], b[ni], acc[mi][ni], 0, 0, 0);
        }
        if (kt < 3) WRITE(cur ^ 1);
        __syncthreads();   // last iter: all As/Bs reads done -> safe to alias
        cur ^= 1;
    }
    if (blockIdx.y >= 4) {
        unsigned short* dst = z;
        const int colbase = (blockIdx.y - 4) * 128 + wc * 64;
        #pragma unroll
        for (int mi = 0; mi < 4; ++mi)
            #pragma unroll
            for (int r = 0; r < 4; ++r) {
                const int row = row0 + wr * 64 + mi * 16 + lg * 4 + r;
                #pragma unroll
                for (int ni = 0; ni < 4; ++ni)
                    dst[(size_t)row * 512 + colbase + ni * 16 + lr] = f2bf(acc[mi][ni][r]);
            }
    } else {
        // xp path: acc -> LDS tile -> conv(4)+SiLU -> ub
        #pragma unroll
        for (int mi = 0; mi < 4; ++mi)
            #pragma unroll
            for (int r = 0; r < 4; ++r) {
                const int trow = wr * 64 + mi * 16 + lg * 4 + r;
                #pragma unroll
                for (int ni = 0; ni < 4; ++ni)
                    xpS[trow][wc * 64 + ni * 16 + lr] = f2bf(acc[mi][ni][r]);
            }
        __syncthreads();
        const int d2 = tid & 63;
        const int dloc = d2 << 1;
        const int dglob = blockIdx.y * 128 + dloc;
        f32x4 wa = *(const f32x4*)(Wc + dglob * 4);
        f32x4 wb = *(const f32x4*)(Wc + dglob * 4 + 4);
        const float b0 = bcv[dglob], b1 = bcv[dglob + 1];
        unsigned int* dst = (unsigned int*)(ub + (size_t)blockIdx.x * 65536 + dglob);
        const int tbase = tid >> 6;
        #pragma unroll 1
        for (int i = 0; i < 32; ++i) {
            const int t = tbase + i * 4;
            float a0 = b0, a1 = b1;
            #pragma unroll
            for (int k = 0; k < 4; ++k) {
                int tt = t - 3 + k;
                if (tt >= 0) {
                    unsigned int pv = *(const unsigned int*)&xpS[tt][dloc];
                    a0 += bf2f((unsigned short)(pv & 0xFFFFu)) * wa[k];
                    a1 += bf2f((unsigned short)(pv >> 16)) * wb[k];
                }
            }
            float u0 = a0 / (1.f + __expf(-a0));
            float u1 = a1 / (1.f + __expf(-a1));
            dst[(size_t)t * 256] = (unsigned int)f2bf(u0) | ((unsigned int)f2bf(u1) << 16);
        }
    }
}

// ---------------------------------------------------------------------------
// x_dbl[16384 x 48] = u_bf[16384 x 512] @ W_xproj_bf[48 x 512]^T  (fp32 out)
__global__ __launch_bounds__(256, 2) void k_xproj(const unsigned short* __restrict__ U,
                                                  const unsigned short* __restrict__ Wb,
                                                  float* __restrict__ xdbl) {
    const int w = threadIdx.x >> 6, l = threadIdx.x & 63;
    const int lr = l & 15, lg = l >> 4;
    const int row0 = blockIdx.x * 64 + w * 16;
    f32x4 acc[3] = {};
    for (int k0 = 0; k0 < 512; k0 += 32) {
        const int ka = k0 + lg * 8;
        bf16x8 a = *(const bf16x8*)(U + (size_t)(row0 + lr) * 512 + ka);
        bf16x8 b[3];
        #pragma unroll
        for (int ni = 0; ni < 3; ++ni)
            b[ni] = *(const bf16x8*)(Wb + (size_t)(ni * 16 + lr) * 512 + ka);
        #pragma unroll
        for (int ni = 0; ni < 3; ++ni)
            acc[ni] = __builtin_amdgcn_mfma_f32_16x16x32_bf16(a, b[ni], acc[ni], 0, 0, 0);
    }
    #pragma unroll
    for (int r = 0; r < 4; ++r) {
        const int row = row0 + lg * 4 + r;
        #pragma unroll
        for (int ni = 0; ni < 3; ++ni)
            xdbl[(size_t)row * 48 + ni * 16 + lr] = acc[ni][r];
    }
}

// ---------------------------------------------------------------------------
// Chunked parallel selective scan v11 (R14-verified session best).
// unroll ladder measured: 1 -> 61us, 2 -> 58.3us (optimum), 4 -> 65.5us
// (regression via scheduler serialization, NOT spill). Keep unroll 2.
__global__ __launch_bounds__(512, 2) void k_scan(const float* __restrict__ xdbl,
                                                 const unsigned short* __restrict__ ub,
                                                 const unsigned short* __restrict__ zb,
                                                 const float* __restrict__ W_dt,
                                                 const float* __restrict__ b_dt,
                                                 const float* __restrict__ A_log,
                                                 const float* __restrict__ Dp,
                                                 unsigned short* __restrict__ yb) {
    __shared__ float bc[128][48];         // [t][ dtr | B | C ]          24 KB
    __shared__ _Float16 dtS[128][128];    // [t][d]                      32 KB
    __shared__ _Float16 cP[3][16][128];   // [chunk][state][dg]          12 KB
    __shared__ _Float16 cH[3][16][128];   //                             12 KB
    const int bn = blockIdx.x >> 2;
    const int d0 = (blockIdx.x & 3) * 128;
    {
        const float* src = xdbl + (size_t)(bn * 128) * 48;
        #pragma unroll
        for (int k = 0; k < 3; ++k) {
            int li = threadIdx.x + k * 512;
            int row = li / 12, c4 = li - row * 12;
            *(f32x4*)(&bc[row][c4 * 4]) = *(const f32x4*)(src + row * 48 + c4 * 4);
        }
    }
    const int dg = threadIdx.x & 127;
    const int c  = threadIdx.x >> 7;
    const int d  = d0 + dg;
    bool fast = true;
    #pragma unroll
    for (int j = 0; j < 16; ++j) {
        float aj = __expf(A_log[d * 16 + j]);
        fast = fast && (fabsf(aj - (float)(j + 1)) < 1e-3f * (float)(j + 1));
    }
    f32x4 wd0 = *(const f32x4*)(W_dt + d * 16);
    f32x4 wd1 = *(const f32x4*)(W_dt + d * 16 + 4);
    f32x4 wd2 = *(const f32x4*)(W_dt + d * 16 + 8);
    f32x4 wd3 = *(const f32x4*)(W_dt + d * 16 + 12);
    const float dbias = b_dt[d];
    const unsigned short* up = ub + (size_t)bn * 65536 + d;
    const unsigned short* zp = zb + (size_t)bn * 65536 + d;
    unsigned short* yp = yb + (size_t)bn * 65536 + d;
    const int t0 = c * 32;
    __syncthreads();
    // --- pass 0: dt -> dtS ---
    #pragma unroll 2
    for (int i = 0; i < 32; ++i) {
        const int t = t0 + i;
        float dl = dbias
                 + dot4(wd0, *(const f32x4*)&bc[t][0])
                 + dot4(wd1, *(const f32x4*)&bc[t][4])
                 + dot4(wd2, *(const f32x4*)&bc[t][8])
                 + dot4(wd3, *(const f32x4*)&bc[t][12]);
        float dt = (dl > 20.f) ? dl : __logf(1.f + __expf(dl));
        dtS[t][dg] = (_Float16)dt;
    }
    float h[16], p[16];
    #pragma unroll
    for (int j = 0; j < 16; ++j) { h[j] = 0.f; p[j] = 1.f; }
    // --- pass 1: local scan (h0=0) + chunk product; chunks 0..2 only ---
    if (c < 3) {
        if (fast) {
            float S = 1.f;
            #pragma unroll 2
            for (int i = 0; i < 32; ++i) {
                const int t = t0 + i;
                float dtv = (float)dtS[t][dg];
                float du  = dtv * bf2f(up[t * 512]);
                float E = __expf(-dtv);
                S *= E;
                float E2 = E * E, E3 = E2 * E, E4 = E2 * E2;
                float E8 = E4 * E4, E12 = E8 * E4;
                f32x4 B0 = *(const f32x4*)&bc[t][16];
                f32x4 B1 = *(const f32x4*)&bc[t][20];
                f32x4 B2 = *(const f32x4*)&bc[t][24];
                f32x4 B3 = *(const f32x4*)&bc[t][28];
                h[0]  = h[0]  * E         + du * B0[0];
                h[1]  = h[1]  * E2        + du * B0[1];
                h[2]  = h[2]  * E3        + du * B0[2];
                h[3]  = h[3]  * E4        + du * B0[3];
                h[4]  = h[4]  * (E4 * E)  + du * B1[0];
                h[5]  = h[5]  * (E4 * E2) + du * B1[1];
                h[6]  = h[6]  * (E4 * E3) + du * B1[2];
                h[7]  = h[7]  * E8        + du * B1[3];
                h[8]  = h[8]  * (E8 * E)  + du * B2[0];
                h[9]  = h[9]  * (E8 * E2) + du * B2[1];
                h[10] = h[10] * (E8 * E3) + du * B2[2];
                h[11] = h[11] * E12       + du * B2[3];
                h[12] = h[12] * (E12 * E) + du * B3[0];
                h[13] = h[13] * (E12 * E2)+ du * B3[1];
                h[14] = h[14] * (E12 * E3)+ du * B3[2];
                h[15] = h[15] * (E12 * E4)+ du * B3[3];
            }
            float S2 = S * S, S3 = S2 * S, S4 = S2 * S2;
            float S8 = S4 * S4, S12 = S8 * S4;
            p[0] = S;        p[1] = S2;        p[2] = S3;        p[3] = S4;
            p[4] = S4 * S;   p[5] = S4 * S2;   p[6] = S4 * S3;   p[7] = S8;
            p[8] = S8 * S;   p[9] = S8 * S2;   p[10] = S8 * S3;  p[11] = S12;
            p[12] = S12 * S; p[13] = S12 * S2; p[14] = S12 * S3; p[15] = S12 * S4;
        } else {
            #pragma unroll 1
            for (int i = 0; i < 32; ++i) {
                const int t = t0 + i;
                float dtv = (float)dtS[t][dg];
                float du  = dtv * bf2f(up[t * 512]);
                #pragma unroll
                for (int j = 0; j < 16; ++j) {
                    float e = __expf(-dtv * __expf(A_log[d * 16 + j]));
                    h[j] = h[j] * e + du * bc[t][16 + j];
                    p[j] *= e;
                }
            }
        }
        #pragma unroll
        for (int s = 0; s < 16; ++s) {
            cP[c][s][dg] = (_Float16)p[s];
            cH[c][s][dg] = (_Float16)h[s];
        }
    }
    __syncthreads();
    // --- Hillis-Steele over chunks 0..2; group-of-4 combine ---
    #pragma unroll
    for (int s = 1; s < 4; s <<= 1) {
        const bool act = (c >= s) && (c < 3);
        __syncthreads();
        if (act) {
            #pragma unroll
            for (int g = 0; g < 4; ++g) {
                #pragma unroll
                for (int k = 0; k < 4; ++k) {
                    const int j = 4 * g + k;
                    float gv = (float)cH[c - s][j][dg];
                    float qv = (float)cP[c - s][j][dg];
                    h[j] += p[j] * gv;
                    p[j] *= qv;
                }
            }
        }
        __syncthreads();
        if (act) {
            #pragma unroll
            for (int j = 0; j < 16; ++j) {
                cP[c][j][dg] = (_Float16)p[j];
                cH[c][j][dg] = (_Float16)h[j];
            }
        }
    }
    __syncthreads();
    #pragma unroll
    for (int j = 0; j < 16; ++j) h[j] = 0.f;
    if (c > 0) {
        #pragma unroll
        for (int j = 0; j < 16; ++j) h[j] = (float)cH[c - 1][j][dg];
    }
    // --- pass 2: rescan from true entry state, emit y ---
    const float dpar = Dp[d];
    if (fast) {
        #pragma unroll 2
        for (int i = 0; i < 32; ++i) {
            const int t = t0 + i;
            float dtv = (float)dtS[t][dg];
            float uv  = bf2f(up[t * 512]);
            float zv  = bf2f(zp[t * 512]);
            float du = dtv * uv;
            float E = __expf(-dtv);
            float E2 = E * E, E3 = E2 * E, E4 = E2 * E2;
            float E8 = E4 * E4, E12 = E8 * E4;
            f32x4 B0 = *(const f32x4*)&bc[t][16];
            f32x4 B1 = *(const f32x4*)&bc[t][20];
            f32x4 B2 = *(const f32x4*)&bc[t][24];
            f32x4 B3 = *(const f32x4*)&bc[t][28];
            f32x4 C0 = *(const f32x4*)&bc[t][32];
            f32x4 C1 = *(const f32x4*)&bc[t][36];
            f32x4 C2 = *(const f32x4*)&bc[t][40];
            f32x4 C3 = *(const f32x4*)&bc[t][44];
            h[0]  = h[0]  * E         + du * B0[0];
            h[1]  = h[1]  * E2        + du * B0[1];
            h[2]  = h[2]  * E3        + du * B0[2];
            h[3]  = h[3]  * E4        + du * B0[3];
            h[4]  = h[4]  * (E4 * E)  + du * B1[0];
            h[5]  = h[5]  * (E4 * E2) + du * B1[1];
            h[6]  = h[6]  * (E4 * E3) + du * B1[2];
            h[7]  = h[7]  * E8        + du * B1[3];
            h[8]  = h[8]  * (E8 * E)  + du * B2[0];
            h[9]  = h[9]  * (E8 * E2) + du * B2[1];
            h[10] = h[10] * (E8 * E3) + du * B2[2];
            h[11] = h[11] * E12       + du * B2[3];
            h[12] = h[12] * (E12 * E) + du * B3[0];
            h[13] = h[13] * (E12 * E2)+ du * B3[1];
            h[14] = h[14] * (E12 * E3)+ du * B3[2];
            h[15] = h[15] * (E12 * E4)+ du * B3[3];
            float y0 = h[0] * C0[0] + h[1] * C0[1] + h[2] * C0[2] + h[3] * C0[3];
            float y1 = h[4] * C1[0] + h[5] * C1[1] + h[6] * C1[2] + h[7] * C1[3];
            float y2 = h[8] * C2[0] + h[9] * C2[1] + h[10] * C2[2] + h[11] * C2[3];
            float y3 = h[12] * C3[0] + h[13] * C3[1] + h[14] * C3[2] + h[15] * C3[3];
            float y = (y0 + y1) + (y2 + y3);
            float yf = (y + uv * dpar) * (zv / (1.f + __expf(-zv)));
            yp[t * 512] = f2bf(yf);
        }
    } else {
        #pragma unroll 1
        for (int i = 0; i < 32; ++i) {
            const int t = t0 + i;
            float dtv = (float)dtS[t][dg];
            float uv  = bf2f(up[t * 512]);
            float zv  = bf2f(zp[t * 512]);
            float du = dtv * uv;
            float y = 0.f;
            #pragma unroll
            for (int j = 0; j < 16; ++j) {
                float e = __expf(-dtv * __expf(A_log[d * 16 + j]));
                h[j] = h[j] * e + du * bc[t][16 + j];
                y += h[j] * bc[t][32 + j];
            }
            float yf = (y + uv * dpar) * (zv / (1.f + __expf(-zv)));
            yp[t * 512] = f2bf(yf);
        }
    }
}

// ---------------------------------------------------------------------------
// out = LayerNorm( y_bf[16384 x 512] @ W_out_bf[256 x 512]^T ) with permuted store.
__global__ __launch_bounds__(256, 2) void k_out_ln(const unsigned short* __restrict__ Y,
                                                   const unsigned short* __restrict__ Wb,
                                                   const float* __restrict__ gamma,
                                                   const float* __restrict__ beta,
                                                   float* __restrict__ out) {
    __shared__ float s_sum[32], s_sq[32];
    const int w = threadIdx.x >> 6, l = threadIdx.x & 63;
    const int lr = l & 15, lg = l >> 4;
    const int row0 = blockIdx.x * 32;
    const int n0 = w * 64;
    f32x4 acc[2][4] = {};
    for (int k0 = 0; k0 < 512; k0 += 32) {
        const int ka = k0 + lg * 8;
        bf16x8 a[2], b[4];
        #pragma unroll
        for (int mi = 0; mi < 2; ++mi)
            a[mi] = *(const bf16x8*)(Y + (size_t)(row0 + mi * 16 + lr) * 512 + ka);
        #pragma unroll
        for (int ni = 0; ni < 4; ++ni)
            b[ni] = *(const bf16x8*)(Wb + (size_t)(n0 + ni * 16 + lr) * 512 + ka);
        #pragma unroll
        for (int mi = 0; mi < 2; ++mi)
            #pragma unroll
            for (int ni = 0; ni < 4; ++ni)
                acc[mi][ni] = __builtin_amdgcn_mfma_f32_16x16x32_bf16(a[mi], b[ni], acc[mi][ni], 0, 0, 0);
    }
    if (threadIdx.x < 32) { s_sum[threadIdx.x] = 0.f; s_sq[threadIdx.x] = 0.f; }
    __syncthreads();
    #pragma unroll
    for (int mi = 0; mi < 2; ++mi)
        #pragma unroll
        for (int r = 0; r < 4; ++r) {
            float s = 0.f, q = 0.f;
            #pragma unroll
            for (int ni = 0; ni < 4; ++ni) { float v = acc[mi][ni][r]; s += v; q += v * v; }
            #pragma unroll
            for (int m = 1; m < 16; m <<= 1) { s += __shfl_xor(s, m, 64); q += __shfl_xor(q, m, 64); }
            if (lr == 0) {
                atomicAdd(&s_sum[mi * 16 + lg * 4 + r], s);
                atomicAdd(&s_sq[mi * 16 + lg * 4 + r], q);
            }
        }
    __syncthreads();
    float g[4], be[4];
    #pragma unroll
    for (int ni = 0; ni < 4; ++ni) {
        g[ni] = gamma[n0 + ni * 16 + lr];
        be[ni] = beta[n0 + ni * 16 + lr];
    }
    #pragma unroll
    for (int mi = 0; mi < 2; ++mi)
        #pragma unroll
        for (int r = 0; r < 4; ++r) {
            const int rl = mi * 16 + lg * 4 + r;
            const int row = row0 + rl;
            const float mu = s_sum[rl] * (1.f / 256.f);
            const float var = s_sq[rl] * (1.f / 256.f) - mu * mu;
            const float rs = rsqrtf(var + 1e-5f);
            const int t = row & 127, bn = row >> 7;
            const int nn = bn & 63, bb = bn >> 6;
            float* orow = out + ((((size_t)(bb * 128 + t)) * 64 + nn) << 8);
            #pragma unroll
            for (int ni = 0; ni < 4; ++ni)
                orow[n0 + ni * 16 + lr] = (acc[mi][ni][r] - mu) * rs * g[ni] + be[ni];
        }
}

// ---------------------------------------------------------------------------
extern "C" void kernel_launch(void* const* d_in, const int* in_sizes, int n_in,
                              void* d_out, int out_size, void* d_ws, size_t ws_size,
                              hipStream_t stream) {
    const float* x      = (const float*)d_in[0];
    const float* W_in   = (const float*)d_in[1];
    const float* W_conv = (const float*)d_in[2];
    const float* b_conv = (const float*)d_in[3];
    const float* W_xprj = (const float*)d_in[4];
    const float* W_dt   = (const float*)d_in[5];
    const float* b_dt   = (const float*)d_in[6];
    const float* A_log  = (const float*)d_in[7];
    const float* D_par  = (const float*)d_in[8];
    const float* W_out  = (const float*)d_in[9];
    const float* gamma  = (const float*)d_in[10];
    const float* beta   = (const float*)d_in[11];
    float* out = (float*)d_out;

    char* ws = (char*)d_ws;
    size_t off = 0;
    auto alloc = [&](size_t bytes) -> void* {
        void* p = ws + off;
        off += (bytes + 255) & ~(size_t)255;
        return p;
    };
    unsigned short* Winb  = (unsigned short*)alloc(1024ull * 256 * 2);
    unsigned short* Wxpb  = (unsigned short*)alloc(48ull * 512 * 2);
    unsigned short* Woutb = (unsigned short*)alloc(256ull * 512 * 2);
    unsigned short* zb    = (unsigned short*)alloc(16384ull * 512 * 2);
    unsigned short* ub    = (unsigned short*)alloc(16384ull * 512 * 2);
    float*          xdbl  = (float*)alloc(16384ull * 48 * 4);
    unsigned short* yb    = (unsigned short*)alloc(16384ull * 512 * 2);
    if (off > ws_size) return;

    k_f2bf3<<<408, 256, 0, stream>>>(W_in, W_xprj, W_out,
                                     (unsigned int*)Winb, (unsigned int*)Wxpb,
                                     (unsigned int*)Woutb);
    k_gemm1<<<dim3(128, 8), 256, 0, stream>>>(x, Winb, W_conv, b_conv, ub, zb);
    k_xproj<<<256, 256, 0, stream>>>(ub, Wxpb, xdbl);
    k_scan<<<512, 512, 0, stream>>>(xdbl, ub, zb, W_dt, b_dt, A_log, D_par, yb);
    k_out_ln<<<512, 256, 0, stream>>>(yb, Woutb, gamma, beta, out);
}